// Round 18
// baseline (152.494 us; speedup 1.0000x reference)
//
#include <hip/hip_runtime.h>
#include <hip/hip_fp16.h>

// Problem constants
#define BATCH   4
#define SEQ     4096
#define DMODEL  1024
#define HDIM    120
#define ROWS_TOTAL (BATCH * SEQ)       // 16384
#define TPB     256                    // 16-row tiles per batch (SEQ/16)

typedef float f32x4 __attribute__((ext_vector_type(4)));
typedef short s16x8 __attribute__((ext_vector_type(8)));

// F layout (fragment-ordered ctx): s16x8 F[global_tile][ks][lane]
//   = ctx_n[tile*16 + (lane&15)][ks*32 + (lane>>4)*8 .. +8]  (bf16)
#define FRAG_PER_B ((size_t)TPB * 4 * 64)
// WF layout (fragment-ordered Wq*wt, bf16): s16x8 WF[(ct*32+ks)*64 + lane]

static __device__ __forceinline__ unsigned short f2bf(float f) {
    unsigned u = __float_as_uint(f);
    u += 0x7FFFu + ((u >> 16) & 1u);   // RNE
    return (unsigned short)(u >> 16);
}
static __device__ __forceinline__ s16x8 pack2x4(f32x4 lo, f32x4 hi) {
    s16x8 r;
#pragma unroll
    for (int i = 0; i < 4; ++i) r[i] = (short)f2bf(lo[i]);
#pragma unroll
    for (int i = 0; i < 4; ++i) r[4 + i] = (short)f2bf(hi[i]);
    return r;
}

// ---------------------------------------------------------------------------
// Kernel W (unchanged): Wq -> WF fragment-ordered bf16, wt folded in.
// ---------------------------------------------------------------------------
__global__ __launch_bounds__(64)
void wq_frag_kernel(const float* __restrict__ Wq, const float* __restrict__ wt,
                    s16x8* __restrict__ WF)
{
    const int lane = threadIdx.x;
    const int l15  = lane & 15;
    const int l4   = lane >> 4;
    const int ct   = blockIdx.x >> 5;
    const int ks   = blockIdx.x & 31;
    const int col  = ct * 16 + l15;

    f32x4 lo = (f32x4){0.f,0.f,0.f,0.f}, hi = lo;
    if (col < HDIM) {
        const float w = wt[col];
        const float* src = Wq + (size_t)col * DMODEL + ks * 32 + l4 * 8;
        lo = *(const f32x4*)(src);
        hi = *(const f32x4*)(src + 4);
#pragma unroll
        for (int i = 0; i < 4; ++i) { lo[i] *= w; hi[i] *= w; }
    }
    WF[((size_t)(ct * 32 + ks)) * 64 + lane] = pack2x4(lo, hi);
}

// ---------------------------------------------------------------------------
// Kernel A v3 (unchanged from R15): context GEMM + bias + L2-norm -> F.
// ---------------------------------------------------------------------------
__global__ __launch_bounds__(512)
void ctx_norm_kernel(const float* __restrict__ query,
                     const s16x8* __restrict__ WF,
                     const float* __restrict__ bq,
                     const float* __restrict__ wt,
                     s16x8* __restrict__ F)
{
    __shared__ unsigned short lA[2][32 * 72];
    __shared__ float lsq[32][4];
    __shared__ unsigned short lt[32][136];

    const int tid  = threadIdx.x;
    const int lane = tid & 63;
    const int wv   = tid >> 6;
    const int wr   = wv & 1;
    const int wc   = wv >> 1;
    const int l15  = lane & 15;
    const int l4   = lane >> 4;
    const int row0 = blockIdx.x * 32;

    const int arow = tid >> 4;
    const int achk = tid & 15;
    const float* aload = query + (size_t)(row0 + arow) * DMODEL + achk * 4;

    f32x4 acc[2];
#pragma unroll
    for (int n = 0; n < 2; ++n) acc[n] = (f32x4){0.f,0.f,0.f,0.f};

    auto stage = [&](int buf, const f32x4& v) {
        const unsigned u0 = (unsigned)f2bf(v[0]) | ((unsigned)f2bf(v[1]) << 16);
        const unsigned u1 = (unsigned)f2bf(v[2]) | ((unsigned)f2bf(v[3]) << 16);
        *(uint2*)&lA[buf][arow * 72 + achk * 4] = make_uint2(u0, u1);
    };

    f32x4 pr = *(const f32x4*)(aload);
    stage(0, pr);

    for (int slab = 0; slab < 16; ++slab) {
        __syncthreads();
        if (slab + 1 < 16) pr = *(const f32x4*)(aload + (slab + 1) * 64);
        const int buf = slab & 1;
#pragma unroll
        for (int ks2 = 0; ks2 < 2; ++ks2) {
            const int ks = slab * 2 + ks2;
            const s16x8 a = *(const s16x8*)&lA[buf][(wr * 16 + l15) * 72 + ks2 * 32 + l4 * 8];
#pragma unroll
            for (int n = 0; n < 2; ++n) {
                const s16x8 bfr = WF[((size_t)((wc * 2 + n) * 32 + ks)) * 64 + lane];
                acc[n] = __builtin_amdgcn_mfma_f32_16x16x32_bf16(a, bfr, acc[n], 0, 0, 0);
            }
        }
        if (slab + 1 < 16) stage(buf ^ 1, pr);
    }

    float sumsq[4] = {0.f,0.f,0.f,0.f};
#pragma unroll
    for (int n = 0; n < 2; ++n) {
        const int col = wc * 32 + n * 16 + l15;
        const float bqv = (col < HDIM) ? bq[col] * wt[col] : 0.f;
#pragma unroll
        for (int r = 0; r < 4; ++r) {
            const float v = acc[n][r] + bqv;
            acc[n][r] = v;
            sumsq[r] += v * v;
        }
    }
#pragma unroll
    for (int r = 0; r < 4; ++r) {
        float s = sumsq[r];
        s += __shfl_xor(s, 1);
        s += __shfl_xor(s, 2);
        s += __shfl_xor(s, 4);
        s += __shfl_xor(s, 8);
        sumsq[r] = s;
    }
    if (l15 == 0) {
#pragma unroll
        for (int r = 0; r < 4; ++r)
            lsq[wr * 16 + l4 * 4 + r][wc] = sumsq[r];
    }
    __syncthreads();
#pragma unroll
    for (int r = 0; r < 4; ++r) {
        const int lr = wr * 16 + l4 * 4 + r;
        const float s = lsq[lr][0] + lsq[lr][1] + lsq[lr][2] + lsq[lr][3];
        const float rinv = 1.f / fmaxf(sqrtf(s), 1e-12f);
#pragma unroll
        for (int n = 0; n < 2; ++n)
            lt[lr][wc * 32 + n * 16 + l15] = f2bf(acc[n][r] * rinv);
    }
    __syncthreads();
    {
        const int tl = wv >> 2;
        const int k4 = wv & 3;
        const s16x8 fr = *(const s16x8*)&lt[tl * 16 + l15][k4 * 32 + l4 * 8];
        F[((size_t)(blockIdx.x * 2 + tl) * 4 + k4) * 64 + lane] = fr;
    }
}

// ---------------------------------------------------------------------------
// Kernel B v8: 64-ROW fused gram+softmax. 256 blocks (1/CU) x 1024 thr.
// Block = 64 rows (4 row-tiles, rfrag[4][4] in registers) x 4096 cols.
// Column fragments are loaded ONCE and shared across all 4 row-tiles in
// registers (16 MFMA per cf load) -> reads drop 4x vs 16-row blocks
// (attacks the serialized per-CU load+store memory pipe, R17 model).
// Phase 1: rowsums (1MB reads, no stores). Phase 2: 4 chunks of 1024 cols:
// compute -> 128KB f16 stash -> 64 full rows x 1KB contiguous NT stores.
// ---------------------------------------------------------------------------
__global__ __launch_bounds__(1024)
void gram64_kernel(const s16x8* __restrict__ F, float* __restrict__ out)
{
    __shared__ unsigned short stash[64 * 1024];   // 128 KB f16, XOR-swizzled
    __shared__ float lsum[64][16];                // 4 KB

    const int tid  = threadIdx.x;
    const int lane = tid & 63;
    const int wv   = tid >> 6;          // 0..15
    const int l15  = lane & 15;
    const int l4   = lane >> 4;
    char* lsb = (char*)&stash[0];

    // XCD swizzle (bijective on 256): 32 contiguous 64-row groups per XCD
    const int u    = ((blockIdx.x & 7) << 5) | (blockIdx.x >> 3);
    const int b    = u >> 6;
    const int rg   = u & 63;            // 64-row group within batch
    const s16x8* Fb = F + (size_t)b * FRAG_PER_B;

    // row fragments for 4 row-tiles — live in registers for BOTH phases
    s16x8 rfrag[4][4];
#pragma unroll
    for (int rt = 0; rt < 4; ++rt)
#pragma unroll
        for (int ks = 0; ks < 4; ++ks)
            rfrag[rt][ks] = Fb[((size_t)(rg * 4 + rt) * 4 + ks) * 64 + lane];

    // ---------------- phase 1: rowsums ----------------
    // wave wv covers col-tiles wv*16 .. +15 (256 cols)
    float rs[4] = {0.f, 0.f, 0.f, 0.f};
    {
        const s16x8* base = Fb + (size_t)(wv * 16) * 256 + lane;
        s16x8 cf0[4], cf1[4];
        auto loadC = [&](s16x8* cf, int t) {
            const s16x8* p = base + (size_t)t * 256;
#pragma unroll
            for (int ks = 0; ks < 4; ++ks) cf[ks] = p[ks * 64];
        };
        auto accum = [&](const s16x8* cf) {
#pragma unroll
            for (int rt = 0; rt < 4; ++rt) {
                f32x4 a = (f32x4){0.f,0.f,0.f,0.f};
#pragma unroll
                for (int ks = 0; ks < 4; ++ks)
                    a = __builtin_amdgcn_mfma_f32_16x16x32_bf16(cf[ks], rfrag[rt][ks], a, 0, 0, 0);
                rs[rt] += (__expf(a[0]) + __expf(a[1])) + (__expf(a[2]) + __expf(a[3]));
            }
        };
        loadC(cf0, 0);
        loadC(cf1, 1);
        for (int t = 0; t < 16; t += 2) {
            accum(cf0);
            if (t + 2 < 16) loadC(cf0, t + 2);
            accum(cf1);
            if (t + 3 < 16) loadC(cf1, t + 3);
        }
    }
    // reduce over l4 groups: rs[rt] per lane covers row (rt*16 + l15)
#pragma unroll
    for (int rt = 0; rt < 4; ++rt) {
        rs[rt] += __shfl_xor(rs[rt], 16);
        rs[rt] += __shfl_xor(rs[rt], 32);
    }
    if (lane < 16) {
#pragma unroll
        for (int rt = 0; rt < 4; ++rt) lsum[rt * 16 + l15][wv] = rs[rt];
    }
    __syncthreads();
    // rinv for this wave's 4 write rows (4wv..4wv+3), uniform across lanes
    float rv[4];
#pragma unroll
    for (int j = 0; j < 4; ++j) {
        const int row = wv * 4 + j;
        float s = 0.f;
#pragma unroll
        for (int w = 0; w < 16; ++w) s += lsum[row][w];
        rv[j] = 1.f / s;
    }

    // ---------------- phase 2: 4 chunks of 1024 cols ----------------
#pragma unroll
    for (int c = 0; c < 4; ++c) {
        if (c > 0) __syncthreads();     // prior chunk's stash reads complete
        // compute: wave wv -> col-tiles c*64 + wv*4 .. +3, all 4 row-tiles
        {
            s16x8 cfA[4], cfB[4];
            auto loadC = [&](s16x8* cf, int i) {
                const s16x8* p = Fb + (size_t)(c * 64 + wv * 4 + i) * 256 + lane;
#pragma unroll
                for (int ks = 0; ks < 4; ++ks) cf[ks] = p[ks * 64];
            };
            auto comp = [&](const s16x8* cf, int i) {
#pragma unroll
                for (int rt = 0; rt < 4; ++rt) {
                    f32x4 a = (f32x4){0.f,0.f,0.f,0.f};
#pragma unroll
                    for (int ks = 0; ks < 4; ++ks)
                        a = __builtin_amdgcn_mfma_f32_16x16x32_bf16(cf[ks], rfrag[rt][ks], a, 0, 0, 0);
                    const __half2 h01 = __floats2half2_rn(__expf(a[0]), __expf(a[1]));
                    const __half2 h23 = __floats2half2_rn(__expf(a[2]), __expf(a[3]));
                    const int row = rt * 16 + l15;
                    const unsigned byte = ((unsigned)(row * 2048 + (wv * 4 + i) * 32 + l4 * 8))
                                          ^ (unsigned)((row & 7) << 4);
                    *(uint2*)(lsb + byte) = make_uint2(*(const unsigned*)&h01,
                                                       *(const unsigned*)&h23);
                }
            };
            loadC(cfA, 0);
            loadC(cfB, 1);
            comp(cfA, 0); loadC(cfA, 2);
            comp(cfB, 1); loadC(cfB, 3);
            comp(cfA, 2);
            comp(cfB, 3);
        }
        __syncthreads();
        // write: wave wv -> local rows 4wv..4wv+3, 4x 1KB contiguous NT each
#pragma unroll
        for (int j = 0; j < 4; ++j) {
            const int r = wv * 4 + j;
            float* ob = out + ((size_t)b * SEQ + rg * 64 + r) * SEQ + c * 1024;
            const unsigned rsw = (unsigned)((r & 7) << 4);
#pragma unroll
            for (int it = 0; it < 4; ++it) {
                const unsigned byte = ((unsigned)(r * 2048 + it * 512 + lane * 8)) ^ rsw;
                const uint2 d = *(const uint2*)(lsb + byte);
                const float2 f01 = __half22float2(*(const __half2*)&d.x);
                const float2 f23 = __half22float2(*(const __half2*)&d.y);
                f32x4 pv;
                pv[0] = f01.x * rv[j];
                pv[1] = f01.y * rv[j];
                pv[2] = f23.x * rv[j];
                pv[3] = f23.y * rv[j];
                __builtin_nontemporal_store(pv, (f32x4*)(ob + it * 256 + lane * 4));
            }
        }
    }
}

extern "C" void kernel_launch(void* const* d_in, const int* in_sizes, int n_in,
                              void* d_out, int out_size, void* d_ws, size_t ws_size,
                              hipStream_t stream)
{
    const float* query = (const float*)d_in[0];
    // d_in[1] = key (unused by the forward)
    const float* Wq    = (const float*)d_in[2];
    const float* bq    = (const float*)d_in[3];
    const float* wt    = (const float*)d_in[4];
    float* out = (float*)d_out;
    s16x8* F  = (s16x8*)d_ws;                               // 4 MiB
    s16x8* WF = (s16x8*)((char*)d_ws + (size_t)4 * 1024 * 1024);  // 256 KiB

    wq_frag_kernel<<<dim3(256), dim3(64), 0, stream>>>(Wq, wt, WF);
    ctx_norm_kernel<<<dim3(ROWS_TOTAL / 32), dim3(512), 0, stream>>>(query, WF, bq, wt, F);
    gram64_kernel<<<dim3(256), dim3(1024), 0, stream>>>(F, out);
}

// Round 19
// 100.984 us; speedup vs baseline: 1.5101x; 1.5101x over previous
//
#include <hip/hip_runtime.h>
#include <hip/hip_fp16.h>

// Problem constants
#define BATCH   4
#define SEQ     4096
#define DMODEL  1024
#define HDIM    120
#define ROWS_TOTAL (BATCH * SEQ)       // 16384
#define TPB     256                    // 16-row tiles per batch (SEQ/16)

typedef float f32x4 __attribute__((ext_vector_type(4)));
typedef short s16x8 __attribute__((ext_vector_type(8)));

// F layout (fragment-ordered ctx): s16x8 F[global_tile][ks][lane]
//   = ctx_n[tile*16 + (lane&15)][ks*32 + (lane>>4)*8 .. +8]  (bf16)
#define FRAG_PER_B ((size_t)TPB * 4 * 64)
// WF layout (fragment-ordered Wq*wt, bf16): s16x8 WF[(ct*32+ks)*64 + lane]

static __device__ __forceinline__ unsigned short f2bf(float f) {
    unsigned u = __float_as_uint(f);
    u += 0x7FFFu + ((u >> 16) & 1u);   // RNE
    return (unsigned short)(u >> 16);
}
static __device__ __forceinline__ s16x8 pack2x4(f32x4 lo, f32x4 hi) {
    s16x8 r;
#pragma unroll
    for (int i = 0; i < 4; ++i) r[i] = (short)f2bf(lo[i]);
#pragma unroll
    for (int i = 0; i < 4; ++i) r[4 + i] = (short)f2bf(hi[i]);
    return r;
}

// ---------------------------------------------------------------------------
// Kernel W: Wq [120][1024] f32 -> WF fragment-ordered bf16, wt folded in.
// ---------------------------------------------------------------------------
__global__ __launch_bounds__(64)
void wq_frag_kernel(const float* __restrict__ Wq, const float* __restrict__ wt,
                    s16x8* __restrict__ WF)
{
    const int lane = threadIdx.x;
    const int l15  = lane & 15;
    const int l4   = lane >> 4;
    const int ct   = blockIdx.x >> 5;
    const int ks   = blockIdx.x & 31;
    const int col  = ct * 16 + l15;

    f32x4 lo = (f32x4){0.f,0.f,0.f,0.f}, hi = lo;
    if (col < HDIM) {
        const float w = wt[col];
        const float* src = Wq + (size_t)col * DMODEL + ks * 32 + l4 * 8;
        lo = *(const f32x4*)(src);
        hi = *(const f32x4*)(src + 4);
#pragma unroll
        for (int i = 0; i < 4; ++i) { lo[i] *= w; hi[i] *= w; }
    }
    WF[((size_t)(ct * 32 + ks)) * 64 + lane] = pack2x4(lo, hi);
}

// ---------------------------------------------------------------------------
// Kernel A v3 (== R15, proven 16us): context = query @ (Wq*wt)^T + bq*wt,
// row-L2-normalized -> F. 512 blocks x 512 thr (2 blocks/CU, 16 waves/CU).
// 64-k slabs: one barrier per 2 K-steps; full-line f32x4 query staging;
// contiguous 1KB WF fragment loads; 1KB contiguous F fragment stores.
// ---------------------------------------------------------------------------
__global__ __launch_bounds__(512)
void ctx_norm_kernel(const float* __restrict__ query,
                     const s16x8* __restrict__ WF,
                     const float* __restrict__ bq,
                     const float* __restrict__ wt,
                     s16x8* __restrict__ F)
{
    __shared__ unsigned short lA[2][32 * 72];   // two 64-k slabs
    __shared__ float lsq[32][4];
    __shared__ unsigned short lt[32][136];

    const int tid  = threadIdx.x;
    const int lane = tid & 63;
    const int wv   = tid >> 6;          // 0..7
    const int wr   = wv & 1;            // row-group (16 rows)
    const int wc   = wv >> 1;           // col quarter (32 cols = 2 tiles)
    const int l15  = lane & 15;
    const int l4   = lane >> 4;
    const int row0 = blockIdx.x * 32;

    const int arow = tid >> 4;          // 0..31
    const int achk = tid & 15;          // 16 x f32x4 = 64 k
    const float* aload = query + (size_t)(row0 + arow) * DMODEL + achk * 4;

    f32x4 acc[2];
#pragma unroll
    for (int n = 0; n < 2; ++n) acc[n] = (f32x4){0.f,0.f,0.f,0.f};

    auto stage = [&](int buf, const f32x4& v) {
        const unsigned u0 = (unsigned)f2bf(v[0]) | ((unsigned)f2bf(v[1]) << 16);
        const unsigned u1 = (unsigned)f2bf(v[2]) | ((unsigned)f2bf(v[3]) << 16);
        *(uint2*)&lA[buf][arow * 72 + achk * 4] = make_uint2(u0, u1);
    };

    f32x4 pr = *(const f32x4*)(aload);
    stage(0, pr);

    for (int slab = 0; slab < 16; ++slab) {
        __syncthreads();                      // slab staged; prev slab reads done
        if (slab + 1 < 16) pr = *(const f32x4*)(aload + (slab + 1) * 64);
        const int buf = slab & 1;
#pragma unroll
        for (int ks2 = 0; ks2 < 2; ++ks2) {
            const int ks = slab * 2 + ks2;
            const s16x8 a = *(const s16x8*)&lA[buf][(wr * 16 + l15) * 72 + ks2 * 32 + l4 * 8];
#pragma unroll
            for (int n = 0; n < 2; ++n) {
                const s16x8 bfr = WF[((size_t)((wc * 2 + n) * 32 + ks)) * 64 + lane];
                acc[n] = __builtin_amdgcn_mfma_f32_16x16x32_bf16(a, bfr, acc[n], 0, 0, 0);
            }
        }
        if (slab + 1 < 16) stage(buf ^ 1, pr);
    }

    // epilogue: + bq*wt, row L2-norm (reduce over l15 lanes, then 4 quarters)
    float sumsq[4] = {0.f,0.f,0.f,0.f};
#pragma unroll
    for (int n = 0; n < 2; ++n) {
        const int col = wc * 32 + n * 16 + l15;
        const float bqv = (col < HDIM) ? bq[col] * wt[col] : 0.f;
#pragma unroll
        for (int r = 0; r < 4; ++r) {
            const float v = acc[n][r] + bqv;
            acc[n][r] = v;
            sumsq[r] += v * v;
        }
    }
#pragma unroll
    for (int r = 0; r < 4; ++r) {
        float s = sumsq[r];
        s += __shfl_xor(s, 1);
        s += __shfl_xor(s, 2);
        s += __shfl_xor(s, 4);
        s += __shfl_xor(s, 8);
        sumsq[r] = s;
    }
    if (l15 == 0) {
#pragma unroll
        for (int r = 0; r < 4; ++r)
            lsq[wr * 16 + l4 * 4 + r][wc] = sumsq[r];
    }
    __syncthreads();
#pragma unroll
    for (int r = 0; r < 4; ++r) {
        const int lr = wr * 16 + l4 * 4 + r;
        const float s = lsq[lr][0] + lsq[lr][1] + lsq[lr][2] + lsq[lr][3];
        const float rinv = 1.f / fmaxf(sqrtf(s), 1e-12f);
#pragma unroll
        for (int n = 0; n < 2; ++n)
            lt[lr][wc * 32 + n * 16 + l15] = f2bf(acc[n][r] * rinv);
    }
    __syncthreads();
    // F store: 8 fragments (2 tiles x 4 k-groups), one per wave, 1KB each
    {
        const int tl = wv >> 2;             // 0..1
        const int k4 = wv & 3;              // 0..3
        const s16x8 fr = *(const s16x8*)&lt[tl * 16 + l15][k4 * 32 + l4 * 8];
        F[((size_t)(blockIdx.x * 2 + tl) * 4 + k4) * 64 + lane] = fr;
    }
}

// ---------------------------------------------------------------------------
// Kernel B (== R11/R15 v4, proven 80us — best of 8 structural variants):
// fused single pass, 1024 blocks x 1024 thr, block = one 16-row tile x 4096
// cols, wave = 256-col strip, depth-3 register prefetch. exp stash -> f16
// LDS (XOR-swizzled); write phase: wave w writes output row w as 16 x 1KB
// contiguous NT stores.
// ---------------------------------------------------------------------------
#define LOADT(dst, t) { const s16x8* _p = base + (size_t)(t) * 256;            \
    dst[0] = _p[0]; dst[1] = _p[64]; dst[2] = _p[128]; dst[3] = _p[192]; }

#define COMPT(src, t) { f32x4 _a = (f32x4){0.f, 0.f, 0.f, 0.f};                \
    _a = __builtin_amdgcn_mfma_f32_16x16x32_bf16(src[0], rfrag[0], _a, 0,0,0); \
    _a = __builtin_amdgcn_mfma_f32_16x16x32_bf16(src[1], rfrag[1], _a, 0,0,0); \
    _a = __builtin_amdgcn_mfma_f32_16x16x32_bf16(src[2], rfrag[2], _a, 0,0,0); \
    _a = __builtin_amdgcn_mfma_f32_16x16x32_bf16(src[3], rfrag[3], _a, 0,0,0); \
    const float _e0 = __expf(_a[0]), _e1 = __expf(_a[1]);                      \
    const float _e2 = __expf(_a[2]), _e3 = __expf(_a[3]);                      \
    rs += (_e0 + _e1) + (_e2 + _e3);                                           \
    const __half2 _h01 = __floats2half2_rn(_e0, _e1);                          \
    const __half2 _h23 = __floats2half2_rn(_e2, _e3);                          \
    unsigned _byte = (unsigned)(l15 * 8192 + cg * 512 + (t) * 32 + l4 * 8);    \
    _byte ^= (unsigned)(l15 << 4);                                             \
    *(uint2*)(lsbase + _byte) =                                                \
        make_uint2(*(const unsigned*)&_h01, *(const unsigned*)&_h23); }

__global__ __launch_bounds__(1024)
void gram_fused_kernel(const s16x8* __restrict__ F, float* __restrict__ out)
{
    __shared__ unsigned short lsE[16][4096];    // f16 stash, 128 KB, swizzled
    __shared__ float lsum[16][16];

    const int tid  = threadIdx.x;
    const int lane = tid & 63;
    const int cg   = tid >> 6;          // col strip 0..15 (256 cols)
    const int l15  = lane & 15;
    const int l4   = lane >> 4;
    char* lsbase = (char*)&lsE[0][0];

    // XCD swizzle (bijective on 1024): 128 contiguous row-tiles per XCD
    const int u    = ((blockIdx.x & 7) << 7) | (blockIdx.x >> 3);
    const int b    = u >> 8;
    const int tr   = u & 255;
    const s16x8* Fb = F + (size_t)b * FRAG_PER_B;

    s16x8 rfrag[4];
#pragma unroll
    for (int ks = 0; ks < 4; ++ks) rfrag[ks] = Fb[((size_t)tr * 4 + ks) * 64 + lane];

    const s16x8* base = Fb + (size_t)(cg * 16) * 256 + lane;

    float rs = 0.f;
    s16x8 cA[4], cB[4], cC[4];
    LOADT(cA, 0)
    LOADT(cB, 1)
    LOADT(cC, 2)
#pragma unroll
    for (int i = 0; i < 6; ++i) {
        const int t = i * 3;
        { COMPT(cA, t)           if (t + 3 < 16) LOADT(cA, t + 3) }
        if (t + 1 < 16) { COMPT(cB, t + 1) if (t + 4 < 16) LOADT(cB, t + 4) }
        if (t + 2 < 16) { COMPT(cC, t + 2) if (t + 5 < 16) LOADT(cC, t + 5) }
    }

    // rowsum partials: l4 groups hold partial sums of row l15
    rs += __shfl_xor(rs, 16);
    rs += __shfl_xor(rs, 32);
    if (lane < 16) lsum[lane][cg] = rs;
    __syncthreads();                     // lsE + lsum complete

    // write phase: wave cg owns output row cg of this tile
    float s = 0.f;
#pragma unroll
    for (int w = 0; w < 16; ++w) s += lsum[cg][w];
    const float rv = 1.f / s;

    float* ob = out + ((size_t)b * SEQ + tr * 16 + cg) * SEQ;
    const unsigned swz = (unsigned)(cg << 4);
#pragma unroll
    for (int it = 0; it < 16; ++it) {
        // read addr un-swizzles -> data fetched is LOGICAL col-chunk lane*4
        const unsigned sbyte = (unsigned)(cg * 8192 + it * 512 + lane * 8) ^ swz;
        const uint2 d = *(const uint2*)(lsbase + sbyte);
        const float2 f01 = __half22float2(*(const __half2*)&d.x);
        const float2 f23 = __half22float2(*(const __half2*)&d.y);
        f32x4 pv;
        pv[0] = f01.x * rv;
        pv[1] = f01.y * rv;
        pv[2] = f23.x * rv;
        pv[3] = f23.y * rv;
        __builtin_nontemporal_store(pv, (f32x4*)(ob + it * 256 + lane * 4));
    }
}

extern "C" void kernel_launch(void* const* d_in, const int* in_sizes, int n_in,
                              void* d_out, int out_size, void* d_ws, size_t ws_size,
                              hipStream_t stream)
{
    const float* query = (const float*)d_in[0];
    // d_in[1] = key (unused by the forward)
    const float* Wq    = (const float*)d_in[2];
    const float* bq    = (const float*)d_in[3];
    const float* wt    = (const float*)d_in[4];
    float* out = (float*)d_out;
    s16x8* F  = (s16x8*)d_ws;                               // 4 MiB
    s16x8* WF = (s16x8*)((char*)d_ws + (size_t)4 * 1024 * 1024);  // 256 KiB

    wq_frag_kernel<<<dim3(256), dim3(64), 0, stream>>>(Wq, wt, WF);
    ctx_norm_kernel<<<dim3(ROWS_TOTAL / 32), dim3(512), 0, stream>>>(query, WF, bq, wt, F);
    gram_fused_kernel<<<dim3(BATCH * TPB), dim3(1024), 0, stream>>>(F, out);
}